// Round 8
// baseline (111.448 us; speedup 1.0000x reference)
//
#include <hip/hip_runtime.h>
#include <hip/hip_fp16.h>

// Problem constants: output (16,2,512,512) f32, target (16,512,512) int32
#define BB   16
#define HH   512
#define WW   512
#define HWSZ (HH * WW)
#define NPIX (BB * HWSZ)
#define LARGE_F 524289.0f  // H*H + W*W + 1
#define NW 16              // u32 words per column (HH/32)
#define GR 8               // rows per loss block (word-aligned: never straddles)
#define NLOSSBLK (BB * HH / GR)  // 1024

// Global bit layout: bitsG[((b*2+sel)*NW + w)*WW + c], bit k of word w = row w*32+k.
// sel 0 = pc mask (x1 > x0), sel 1 = gt mask (target == 1).

// ---------------- Kernel 1: mask pack + pointwise error (fp16) ----------------
// Also zeroes the loss completion counter (runs before loss in stream order).
__global__ __launch_bounds__(512) void pack_kernel(
    const float* __restrict__ out4,
    const int* __restrict__ target,
    unsigned int* __restrict__ bitsG,
    __half* __restrict__ eG,
    unsigned int* __restrict__ cnt) {
  __shared__ unsigned char mbyte[32 * 256];  // 8 KiB

  if (blockIdx.x == 0 && blockIdx.y == 0 && threadIdx.x == 0) *cnt = 0u;

  const int w    = blockIdx.x >> 1;   // word-row band (0..15)
  const int half = blockIdx.x & 1;    // col half
  const int b    = blockIdx.y;
  const int c0   = half * 256;
  const float* ch0 = out4 + (size_t)(b * 2) * HWSZ;
  const float* ch1 = ch0 + HWSZ;
  const int* tb = target + (size_t)b * HWSZ;
  __half* eb = eG + (size_t)b * HWSZ;

  // load 32 rows x 256 cols, 2048 quads, 512 threads -> 4 iters
#pragma unroll
  for (int s = 0; s < 4; ++s) {
    int q  = s * 512 + threadIdx.x;
    int i  = q >> 6;            // 64 quads per row
    int cq = (q & 63) * 4;
    int g  = (w * 32 + i) * WW + c0 + cq;
    float4 a0 = *(const float4*)(ch0 + g);
    float4 a1 = *(const float4*)(ch1 + g);
    int4   t4 = *(const int4*)(tb + g);
    unsigned p = 0;
    p |= (unsigned)(((a1.x > a0.x) ? 1u : 0u) | ((t4.x == 1) ? 2u : 0u));
    p |= (unsigned)(((a1.y > a0.y) ? 1u : 0u) | ((t4.y == 1) ? 2u : 0u)) << 8;
    p |= (unsigned)(((a1.z > a0.z) ? 1u : 0u) | ((t4.z == 1) ? 2u : 0u)) << 16;
    p |= (unsigned)(((a1.w > a0.w) ? 1u : 0u) | ((t4.w == 1) ? 2u : 0u)) << 24;
    *(unsigned*)&mbyte[i * 256 + cq] = p;

    // pointwise error e = (p1 - y1)^2, p1 = 1/(1+exp(x0-x1)); store fp16
    float d0, d1, d2, d3;
    d0 = 1.0f / (1.0f + expf(a0.x - a1.x)) - ((t4.x == 1) ? 1.0f : 0.0f);
    d1 = 1.0f / (1.0f + expf(a0.y - a1.y)) - ((t4.y == 1) ? 1.0f : 0.0f);
    d2 = 1.0f / (1.0f + expf(a0.z - a1.z)) - ((t4.z == 1) ? 1.0f : 0.0f);
    d3 = 1.0f / (1.0f + expf(a0.w - a1.w)) - ((t4.w == 1) ? 1.0f : 0.0f);
    __half2 e01 = __floats2half2_rn(d0 * d0, d1 * d1);
    __half2 e23 = __floats2half2_rn(d2 * d2, d3 * d3);
    *(__half2*)(eb + g)     = e01;
    *(__half2*)(eb + g + 2) = e23;
  }
  __syncthreads();

  // pack: thread t -> column c = t&255, sel = t>>8 (all 512 active)
  {
    int c   = threadIdx.x & 255;
    int sel = threadIdx.x >> 8;
    unsigned wd = 0;
#pragma unroll
    for (int k = 0; k < 32; ++k) {
      unsigned mb = mbyte[k * 256 + c];
      wd |= ((mb >> sel) & 1u) << k;
    }
    bitsG[(size_t)((b * 2 + sel) * NW + w) * WW + c0 + c] = wd;
  }
}

// Column distances for 8 word-aligned rows [i0, i0+7] of column j, one mask.
// 2 full probes (up at i0, down at i0+7) + recurrences. Exact; LDS band with
// global fallback beyond it.
__device__ __forceinline__ void colprobe8(const unsigned (*lb)[WW],
                                          const unsigned* __restrict__ gcol,
                                          int wlo, int whi, int j, int i0,
                                          int* __restrict__ rr) {
  const int w = i0 >> 5, bp = i0 & 31;   // bp in {0,8,16,24}
  const unsigned cur = lb[w - wlo][j];

  // full probe up from row i0 (nearest 0-bit at row <= i0)
  unsigned zu = ~cur & (0xFFFFFFFFu >> (31 - bp));
  int up = 0xFFFF;
  if (zu) {
    up = bp - (31 - __clz(zu));
  } else {
    for (int ww = w - 1; ww >= 0; --ww) {
      unsigned z = ~((ww >= wlo) ? lb[ww - wlo][j] : gcol[ww * WW]);
      if (z) { up = i0 - (ww * 32 + 31 - __clz(z)); break; }
    }
  }
  // full probe down from row i0+7 (nearest 0-bit at row >= i0+7)
  const int bp7 = bp + 7;
  unsigned zd = ~cur & (0xFFFFFFFFu << bp7);
  int dn = 0xFFFF;
  if (zd) {
    dn = (__ffs((int)zd) - 1) - bp7;
  } else {
    for (int ww = w + 1; ww < NW; ++ww) {
      unsigned z = ~((ww <= whi) ? lb[ww - wlo][j] : gcol[ww * WW]);
      if (z) { dn = ww * 32 + (__ffs((int)z) - 1) - (i0 + 7); break; }
    }
  }

  const unsigned bits8 = (cur >> bp) & 0xFFu;
  int ups[GR], dns[GR];
  ups[0] = up;
  for (int k = 1; k < GR; ++k)
    ups[k] = ((bits8 >> k) & 1u) ? ups[k - 1] + 1 : 0;
  dns[GR - 1] = dn;
  for (int k = GR - 2; k >= 0; --k)
    dns[k] = ((bits8 >> k) & 1u) ? dns[k + 1] + 1 : 0;
#pragma unroll
  for (int k = 0; k < GR; ++k) rr[k] = min(ups[k], dns[k]);
}

// ---------------- Kernel 2: col EDT + row EDT + loss + fused final reduce ----------------
__global__ __launch_bounds__(512) void loss_kernel(
    const __half* __restrict__ eG,
    const unsigned int* __restrict__ bitsG,
    float* __restrict__ partials,
    unsigned int* __restrict__ cnt,
    float* __restrict__ d_out) {
  __shared__ unsigned lbits[2][3][WW];  // 12 KiB band: [sel][wrel][col]
  __shared__ float2 fv[GR][WW];         // 32 KiB: (fpc, fgt) per row/col
  __shared__ float ssum[8];
  __shared__ int slast;

  const int b  = blockIdx.x >> 6;
  const int i0 = (blockIdx.x & 63) * GR;
  const int j  = threadIdx.x;

  const int wc  = i0 >> 5;
  const int wlo = max(0, wc - 1);
  const int whi = min(NW - 1, wc + 1);
  const int nwr = whi - wlo + 1;

  // ---- stage bits band ----
  const unsigned* gb = bitsG + (size_t)(b * 2) * NW * WW;
  for (int idx = threadIdx.x; idx < nwr * 2 * WW; idx += 512) {
    int c    = idx & (WW - 1);
    int rest = idx >> 9;
    int wrel = rest >> 1;
    int sel  = rest & 1;
    lbits[sel][wrel][c] = gb[(size_t)(sel * NW + wlo + wrel) * WW + c];
  }

  // prefetch pointwise errors (fp16; consumed at the end)
  const __half* ep = eG + (size_t)b * HWSZ + (size_t)i0 * WW;
  float ev[GR];
#pragma unroll
  for (int rw = 0; rw < GR; ++rw) ev[rw] = __half2float(ep[rw * WW + j]);
  __syncthreads();

  // ---- column distances: 2 full probes + recurrence per mask ----
  const unsigned* gpc = gb + j;
  const unsigned* ggt = gb + NW * WW + j;
  int rpc[GR], rgt[GR];
  colprobe8(lbits[0], gpc, wlo, whi, j, i0, rpc);
  colprobe8(lbits[1], ggt, wlo, whi, j, i0, rgt);

  float bpc[GR], bgt[GR];
#pragma unroll
  for (int rw = 0; rw < GR; ++rw) {
    float fpc = (rpc[rw] >= 512) ? LARGE_F : (float)(rpc[rw] * rpc[rw]);
    float fgt = (rgt[rw] >= 512) ? LARGE_F : (float)(rgt[rw] * rgt[rw]);
    fv[rw][j] = make_float2(fpc, fgt);
    bpc[rw] = fpc; bgt[rw] = fgt;
  }
  __syncthreads();

  // ---- row pass: exact pruned probe ----
  for (int r = 1; r < WW; ++r) {
    float rr = (float)(r * r);
    float mx = 0.0f;
#pragma unroll
    for (int rw = 0; rw < GR; ++rw) mx = fmaxf(mx, fmaxf(bpc[rw], bgt[rw]));
    if (rr >= mx) break;
    int jl = j - r, jr = j + r;
    if (jl >= 0) {
#pragma unroll
      for (int rw = 0; rw < GR; ++rw) {
        float2 a = fv[rw][jl];
        bpc[rw] = fminf(bpc[rw], a.x + rr);
        bgt[rw] = fminf(bgt[rw], a.y + rr);
      }
    }
    if (jr < WW) {
#pragma unroll
      for (int rw = 0; rw < GR; ++rw) {
        float2 a = fv[rw][jr];
        bpc[rw] = fminf(bpc[rw], a.x + rr);
        bgt[rw] = fminf(bgt[rw], a.y + rr);
      }
    }
  }

  // ---- loss ----
  float contrib = 0.0f;
#pragma unroll
  for (int rw = 0; rw < GR; ++rw) contrib += ev[rw] * (bpc[rw] + bgt[rw]);
  contrib *= (1.0f / (float)NPIX);

  // block reduction
  for (int off = 32; off > 0; off >>= 1) contrib += __shfl_down(contrib, off);
  int lane = threadIdx.x & 63;
  int wave = threadIdx.x >> 6;
  if (lane == 0) ssum[wave] = contrib;
  __syncthreads();
  if (threadIdx.x == 0) {
    float s = 0.0f;
#pragma unroll
    for (int w = 0; w < 8; ++w) s += ssum[w];
    partials[blockIdx.x] = s;
    __threadfence();                       // release partial to device scope
    unsigned old = atomicAdd(cnt, 1u);     // device-scope
    slast = (old == NLOSSBLK - 1) ? 1 : 0;
  }
  __syncthreads();

  // ---- last arriving block: final reduce of 1024 partials ----
  if (slast) {
    __threadfence();  // acquire: all partials visible
    float s = partials[threadIdx.x] + partials[threadIdx.x + 512];
    for (int off = 32; off > 0; off >>= 1) s += __shfl_down(s, off);
    if (lane == 0) ssum[wave] = s;
    __syncthreads();
    if (threadIdx.x == 0) {
      float t = 0.0f;
#pragma unroll
      for (int w = 0; w < 8; ++w) t += ssum[w];
      *d_out = t;
    }
  }
}

extern "C" void kernel_launch(void* const* d_in, const int* in_sizes, int n_in,
                              void* d_out, int out_size, void* d_ws, size_t ws_size,
                              hipStream_t stream) {
  const float* out4 = (const float*)d_in[0];
  const int* target = (const int*)d_in[1];
  unsigned int* bitsG = (unsigned int*)d_ws;              // 1 MiB
  __half* eG = (__half*)(bitsG + BB * 2 * NW * WW);       // 8 MiB
  float* partials = (float*)(eG + NPIX);                  // 4 KiB
  unsigned int* cnt = (unsigned int*)(partials + NLOSSBLK);
  float* out = (float*)d_out;

  dim3 grid1(32, BB);  // (band, col-half) x image = 512 blocks
  pack_kernel<<<grid1, 512, 0, stream>>>(out4, target, bitsG, eG, cnt);

  loss_kernel<<<NLOSSBLK, 512, 0, stream>>>(eG, bitsG, partials, cnt, out);
}

// Round 9
// 94.954 us; speedup vs baseline: 1.1737x; 1.1737x over previous
//
#include <hip/hip_runtime.h>
#include <hip/hip_fp16.h>

// Problem constants: output (16,2,512,512) f32, target (16,512,512) int32
#define BB   16
#define HH   512
#define WW   512
#define HWSZ (HH * WW)
#define NPIX (BB * HWSZ)
#define LARGE_F 524289.0f  // H*H + W*W + 1
#define NW 16              // u32 words per column (HH/32)
#define GR 8               // rows per loss block (word-aligned: never straddles)
#define NLOSSBLK (BB * HH / GR)  // 1024

// Global bit layout: bitsG[((b*2+sel)*NW + w)*WW + c], bit k of word w = row w*32+k.
// sel 0 = pc mask (x1 > x0), sel 1 = gt mask (target == 1).

// ---------------- Kernel 1: mask pack + pointwise error (fp16) ----------------
__global__ __launch_bounds__(512) void pack_kernel(
    const float* __restrict__ out4,
    const int* __restrict__ target,
    unsigned int* __restrict__ bitsG,
    __half* __restrict__ eG) {
  __shared__ unsigned char mbyte[32 * 256];  // 8 KiB

  const int w    = blockIdx.x >> 1;   // word-row band (0..15)
  const int half = blockIdx.x & 1;    // col half
  const int b    = blockIdx.y;
  const int c0   = half * 256;
  const float* ch0 = out4 + (size_t)(b * 2) * HWSZ;
  const float* ch1 = ch0 + HWSZ;
  const int* tb = target + (size_t)b * HWSZ;
  __half* eb = eG + (size_t)b * HWSZ;

  // load 32 rows x 256 cols, 2048 quads, 512 threads -> 4 iters
#pragma unroll
  for (int s = 0; s < 4; ++s) {
    int q  = s * 512 + threadIdx.x;
    int i  = q >> 6;            // 64 quads per row
    int cq = (q & 63) * 4;
    int g  = (w * 32 + i) * WW + c0 + cq;
    float4 a0 = *(const float4*)(ch0 + g);
    float4 a1 = *(const float4*)(ch1 + g);
    int4   t4 = *(const int4*)(tb + g);
    unsigned p = 0;
    p |= (unsigned)(((a1.x > a0.x) ? 1u : 0u) | ((t4.x == 1) ? 2u : 0u));
    p |= (unsigned)(((a1.y > a0.y) ? 1u : 0u) | ((t4.y == 1) ? 2u : 0u)) << 8;
    p |= (unsigned)(((a1.z > a0.z) ? 1u : 0u) | ((t4.z == 1) ? 2u : 0u)) << 16;
    p |= (unsigned)(((a1.w > a0.w) ? 1u : 0u) | ((t4.w == 1) ? 2u : 0u)) << 24;
    *(unsigned*)&mbyte[i * 256 + cq] = p;

    // pointwise error e = (p1 - y1)^2, p1 = 1/(1+exp(x0-x1)); store fp16
    float d0, d1, d2, d3;
    d0 = 1.0f / (1.0f + expf(a0.x - a1.x)) - ((t4.x == 1) ? 1.0f : 0.0f);
    d1 = 1.0f / (1.0f + expf(a0.y - a1.y)) - ((t4.y == 1) ? 1.0f : 0.0f);
    d2 = 1.0f / (1.0f + expf(a0.z - a1.z)) - ((t4.z == 1) ? 1.0f : 0.0f);
    d3 = 1.0f / (1.0f + expf(a0.w - a1.w)) - ((t4.w == 1) ? 1.0f : 0.0f);
    __half2 e01 = __floats2half2_rn(d0 * d0, d1 * d1);
    __half2 e23 = __floats2half2_rn(d2 * d2, d3 * d3);
    *(__half2*)(eb + g)     = e01;
    *(__half2*)(eb + g + 2) = e23;
  }
  __syncthreads();

  // pack: thread t -> column c = t&255, sel = t>>8 (all 512 active)
  {
    int c   = threadIdx.x & 255;
    int sel = threadIdx.x >> 8;
    unsigned wd = 0;
#pragma unroll
    for (int k = 0; k < 32; ++k) {
      unsigned mb = mbyte[k * 256 + c];
      wd |= ((mb >> sel) & 1u) << k;
    }
    bitsG[(size_t)((b * 2 + sel) * NW + w) * WW + c0 + c] = wd;
  }
}

// Column distances for 8 word-aligned rows [i0, i0+7] of column j, one mask.
// 2 full probes (up at i0, down at i0+7) + recurrences. Exact; LDS band with
// global fallback beyond it.
__device__ __forceinline__ void colprobe8(const unsigned (*lb)[WW],
                                          const unsigned* __restrict__ gcol,
                                          int wlo, int whi, int j, int i0,
                                          int* __restrict__ rr) {
  const int w = i0 >> 5, bp = i0 & 31;   // bp in {0,8,16,24}
  const unsigned cur = lb[w - wlo][j];

  // full probe up from row i0 (nearest 0-bit at row <= i0)
  unsigned zu = ~cur & (0xFFFFFFFFu >> (31 - bp));
  int up = 0xFFFF;
  if (zu) {
    up = bp - (31 - __clz(zu));
  } else {
    for (int ww = w - 1; ww >= 0; --ww) {
      unsigned z = ~((ww >= wlo) ? lb[ww - wlo][j] : gcol[ww * WW]);
      if (z) { up = i0 - (ww * 32 + 31 - __clz(z)); break; }
    }
  }
  // full probe down from row i0+7 (nearest 0-bit at row >= i0+7)
  const int bp7 = bp + 7;
  unsigned zd = ~cur & (0xFFFFFFFFu << bp7);
  int dn = 0xFFFF;
  if (zd) {
    dn = (__ffs((int)zd) - 1) - bp7;
  } else {
    for (int ww = w + 1; ww < NW; ++ww) {
      unsigned z = ~((ww <= whi) ? lb[ww - wlo][j] : gcol[ww * WW]);
      if (z) { dn = ww * 32 + (__ffs((int)z) - 1) - (i0 + 7); break; }
    }
  }

  const unsigned bits8 = (cur >> bp) & 0xFFu;
  int ups[GR], dns[GR];
  ups[0] = up;
  for (int k = 1; k < GR; ++k)
    ups[k] = ((bits8 >> k) & 1u) ? ups[k - 1] + 1 : 0;
  dns[GR - 1] = dn;
  for (int k = GR - 2; k >= 0; --k)
    dns[k] = ((bits8 >> k) & 1u) ? dns[k + 1] + 1 : 0;
#pragma unroll
  for (int k = 0; k < GR; ++k) rr[k] = min(ups[k], dns[k]);
}

// ---------------- Kernel 2: col EDT (from bits) + row EDT + loss ----------------
// Band is stored [wrel][sel-interleaved by pairs]: laid out so global rows
// (sel*NW + w) for both sels over [wlo..whi] can be fetched with uint4 loads.
__global__ __launch_bounds__(512) void loss_kernel(
    const __half* __restrict__ eG,
    const unsigned int* __restrict__ bitsG,
    float* __restrict__ partials) {
  __shared__ unsigned lbits[2][5][WW];  // 20 KiB band: [sel][wrel][col]
  __shared__ float2 fv[GR][WW];         // 32 KiB: (fpc, fgt) per row/col
  __shared__ float ssum[8];

  const int b  = blockIdx.x >> 6;
  const int i0 = (blockIdx.x & 63) * GR;
  const int j  = threadIdx.x;

  const int wc  = i0 >> 5;
  const int wlo = max(0, wc - 2);
  const int whi = min(NW - 1, wc + 2);
  const int nwr = whi - wlo + 1;

  // prefetch pointwise errors first (independent chain; latency overlaps staging)
  const __half* ep = eG + (size_t)b * HWSZ + (size_t)i0 * WW;
  float ev[GR];
#pragma unroll
  for (int rw = 0; rw < GR; ++rw) ev[rw] = __half2float(ep[rw * WW + j]);

  // ---- stage bits band with uint4 loads ----
  // nwr*2 word-rows x 512 cols = nwr*2*128 uint4s (<= 1280), 512 threads -> <=3 iters
  const unsigned* gb = bitsG + (size_t)(b * 2) * NW * WW;
  const int nquad = nwr * 2 * (WW / 4);
  for (int idx = threadIdx.x; idx < nquad; idx += 512) {
    int cq   = (idx & 127) * 4;          // column quad
    int rest = idx >> 7;                 // 0..(nwr*2-1)
    int wrel = rest >> 1;
    int sel  = rest & 1;
    uint4 v = *(const uint4*)(gb + (size_t)(sel * NW + wlo + wrel) * WW + cq);
    *(uint4*)&lbits[sel][wrel][cq] = v;
  }
  __syncthreads();

  // ---- column distances: 2 full probes + recurrence per mask ----
  const unsigned* gpc = gb + j;
  const unsigned* ggt = gb + NW * WW + j;
  int rpc[GR], rgt[GR];
  colprobe8(lbits[0], gpc, wlo, whi, j, i0, rpc);
  colprobe8(lbits[1], ggt, wlo, whi, j, i0, rgt);

  float bpc[GR], bgt[GR];
#pragma unroll
  for (int rw = 0; rw < GR; ++rw) {
    float fpc = (rpc[rw] >= 512) ? LARGE_F : (float)(rpc[rw] * rpc[rw]);
    float fgt = (rgt[rw] >= 512) ? LARGE_F : (float)(rgt[rw] * rgt[rw]);
    fv[rw][j] = make_float2(fpc, fgt);
    bpc[rw] = fpc; bgt[rw] = fgt;
  }
  __syncthreads();

  // ---- row pass: exact pruned probe ----
  for (int r = 1; r < WW; ++r) {
    float rr = (float)(r * r);
    float mx = 0.0f;
#pragma unroll
    for (int rw = 0; rw < GR; ++rw) mx = fmaxf(mx, fmaxf(bpc[rw], bgt[rw]));
    if (rr >= mx) break;
    int jl = j - r, jr = j + r;
    if (jl >= 0) {
#pragma unroll
      for (int rw = 0; rw < GR; ++rw) {
        float2 a = fv[rw][jl];
        bpc[rw] = fminf(bpc[rw], a.x + rr);
        bgt[rw] = fminf(bgt[rw], a.y + rr);
      }
    }
    if (jr < WW) {
#pragma unroll
      for (int rw = 0; rw < GR; ++rw) {
        float2 a = fv[rw][jr];
        bpc[rw] = fminf(bpc[rw], a.x + rr);
        bgt[rw] = fminf(bgt[rw], a.y + rr);
      }
    }
  }

  // ---- loss ----
  float contrib = 0.0f;
#pragma unroll
  for (int rw = 0; rw < GR; ++rw) contrib += ev[rw] * (bpc[rw] + bgt[rw]);
  contrib *= (1.0f / (float)NPIX);

  // block reduction
  for (int off = 32; off > 0; off >>= 1) contrib += __shfl_down(contrib, off);
  int lane = threadIdx.x & 63;
  int wave = threadIdx.x >> 6;
  if (lane == 0) ssum[wave] = contrib;
  __syncthreads();
  if (threadIdx.x == 0) {
    float s = 0.0f;
#pragma unroll
    for (int w = 0; w < 8; ++w) s += ssum[w];
    partials[blockIdx.x] = s;
  }
}

// ---------------- Kernel 3: final reduce ----------------
__global__ __launch_bounds__(1024) void reduce_kernel(
    const float* __restrict__ partials, float* __restrict__ d_out) {
  __shared__ float ssum[16];
  float s = partials[threadIdx.x];  // NLOSSBLK == 1024
  for (int off = 32; off > 0; off >>= 1) s += __shfl_down(s, off);
  int lane = threadIdx.x & 63;
  int wave = threadIdx.x >> 6;
  if (lane == 0) ssum[wave] = s;
  __syncthreads();
  if (threadIdx.x == 0) {
    float t = 0.0f;
#pragma unroll
    for (int w = 0; w < 16; ++w) t += ssum[w];
    *d_out = t;
  }
}

extern "C" void kernel_launch(void* const* d_in, const int* in_sizes, int n_in,
                              void* d_out, int out_size, void* d_ws, size_t ws_size,
                              hipStream_t stream) {
  const float* out4 = (const float*)d_in[0];
  const int* target = (const int*)d_in[1];
  unsigned int* bitsG = (unsigned int*)d_ws;              // 1 MiB
  __half* eG = (__half*)(bitsG + BB * 2 * NW * WW);       // 8 MiB
  float* partials = (float*)(eG + NPIX);                  // 4 KiB
  float* out = (float*)d_out;

  dim3 grid1(32, BB);  // (band, col-half) x image = 512 blocks
  pack_kernel<<<grid1, 512, 0, stream>>>(out4, target, bitsG, eG);

  loss_kernel<<<NLOSSBLK, 512, 0, stream>>>(eG, bitsG, partials);

  reduce_kernel<<<1, 1024, 0, stream>>>(partials, out);
}